// Round 1
// baseline (113.393 us; speedup 1.0000x reference)
//
#include <hip/hip_runtime.h>
#include <cstdint>
#include <cstddef>

// Fused Swin-style window attention for MI355X (gfx950).
// B=4096 windows, N=64 tokens, C=128, H=4 heads, hd=32.
// One block per window, 4 waves, wave = head. All GEMMs in bf16 MFMA, f32 accum.
//
// Layout algebra (16x16 MFMA family, verified C-layout: col=lane&15, row=(lane>>4)*4+i):
//  - qkv GEMM computes Q^T,K^T (swapped operands) and V (normal) from the same
//    swizzled x tile in LDS.
//  - S^T = K·Q^T and out^T = V^T·P^T use mfma_f32_16x16x16bf16_1k whose A/B frag
//    layout (row=lane&15, k=(lane>>4)*4+j) equals the transposed C-layout ->
//    all attention operands are lane-local repacks; no LDS round trip for Q/K/V/P.
//  - softmax: 16 lane-local values per row + shfl_xor(16), shfl_xor(32).

typedef float f32x4 __attribute__((ext_vector_type(4)));
typedef __bf16 bf16x8 __attribute__((ext_vector_type(8)));
typedef short s16x4 __attribute__((ext_vector_type(4)));
typedef unsigned short u16x8 __attribute__((ext_vector_type(8)));
typedef unsigned short u16x4 __attribute__((ext_vector_type(4)));

#define NTOK 64
#define CDIM 128

__device__ __forceinline__ unsigned short f2bf(float f) {
  union { float f; unsigned u; } v; v.f = f;
  unsigned r = (v.u + 0x7fffu + ((v.u >> 16) & 1u)) >> 16;  // RNE
  return (unsigned short)r;
}
__device__ __forceinline__ unsigned pk2(float a, float b) {
  return (unsigned)f2bf(a) | ((unsigned)f2bf(b) << 16);
}
__device__ __forceinline__ u16x4 pack4(f32x4 v) {
  u16x4 r; r[0] = f2bf(v[0]); r[1] = f2bf(v[1]); r[2] = f2bf(v[2]); r[3] = f2bf(v[3]);
  return r;
}
__device__ __forceinline__ f32x4 mfma32(u16x8 a, u16x8 b, f32x4 c) {
  return __builtin_amdgcn_mfma_f32_16x16x32_bf16(
      __builtin_bit_cast(bf16x8, a), __builtin_bit_cast(bf16x8, b), c, 0, 0, 0);
}
__device__ __forceinline__ f32x4 mfma16(u16x4 a, u16x4 b, f32x4 c) {
  return __builtin_amdgcn_mfma_f32_16x16x16bf16_1k(
      __builtin_bit_cast(s16x4, a), __builtin_bit_cast(s16x4, b), c, 0, 0, 0);
}

// ---------------- prep: transpose/convert weights, expand rel-pos bias ----------------
// ws layout: [0,98304)       wqkv_t bf16 [384 cols][128 k]  (scale folded into Q cols)
//            [98304,131072)  wproj_t bf16 [128 cols][128 k]
//            [131072,196608) bias_st f32 [h][mtk][ntq][lane][i]  (S^T C-layout frags)
__global__ void prep_kernel(const float* __restrict__ wqkv, const float* __restrict__ wproj,
                            const float* __restrict__ btab,
                            unsigned short* __restrict__ wqkvt,
                            unsigned short* __restrict__ wprojt,
                            float* __restrict__ biasst) {
  int t = blockIdx.x * 256 + threadIdx.x;
  if (t < 49152) {
    int c = t >> 7, k = t & 127;
    float v = wqkv[k * 384 + c];
    if (c < 128) v *= 0.17677669529663687f;  // 1/sqrt(32)
    wqkvt[t] = f2bf(v);
  } else if (t < 65536) {
    int t2 = t - 49152;
    int c = t2 >> 7, k = t2 & 127;
    wprojt[t2] = f2bf(wproj[k * 128 + c]);
  } else if (t < 81920) {
    int t3 = t - 65536;
    int i = t3 & 3, lane = (t3 >> 2) & 63, nq = (t3 >> 8) & 3, mk = (t3 >> 10) & 3, h = t3 >> 12;
    int key = mk * 16 + ((lane >> 4) << 2) + i;   // S^T row (C-layout)
    int q   = nq * 16 + (lane & 15);              // S^T col
    int idx = ((q >> 3) - (key >> 3) + 7) * 15 + ((q & 7) - (key & 7) + 7);
    biasst[t3] = btab[idx * 4 + h];
  }
}

// ---------------- fused attention ----------------
__global__ __launch_bounds__(256) void attn_kernel(
    const float* __restrict__ x, const unsigned short* __restrict__ wqkvt,
    const unsigned short* __restrict__ wprojt, const float* __restrict__ biasst,
    const float* __restrict__ bproj, float* __restrict__ out) {
  __shared__ unsigned short xs[NTOK * CDIM];  // 16 KB, swizzled; reused for attn-out
  const int tid = threadIdx.x;
  const int lane = tid & 63;
  const int h = tid >> 6;        // wave = head
  const int g = lane >> 4;
  const int q15 = lane & 15;
  const size_t wbase = (size_t)blockIdx.x * (NTOK * CDIM);

  // ---- stage x (f32 -> bf16, swizzled row-major [64][128]) ----
  {
    const int row = tid >> 2;
    const int cb = (tid & 3) * 32;
    const float4* xp = (const float4*)(x + wbase + row * CDIM + cb);
#pragma unroll
    for (int u = 0; u < 4; ++u) {
      float4 a = xp[2 * u], b = xp[2 * u + 1];
      uint4 p;
      p.x = pk2(a.x, a.y); p.y = pk2(a.z, a.w);
      p.z = pk2(b.x, b.y); p.w = pk2(b.z, b.w);
      int byte = row * 256 + (((cb * 2) + u * 16) ^ ((row & 7) << 4));
      *(uint4*)((char*)xs + byte) = p;
    }
  }
  __syncthreads();

  const f32x4 zero4 = {0.f, 0.f, 0.f, 0.f};

  // ---- qkv GEMM: Q^T,K^T = W^T · x^T ; V = x · Wv ----
  f32x4 qt[2][4], kt[2][4], vv[4][2];
#pragma unroll
  for (int m = 0; m < 2; ++m)
#pragma unroll
    for (int t = 0; t < 4; ++t) { qt[m][t] = zero4; kt[m][t] = zero4; }
#pragma unroll
  for (int t = 0; t < 4; ++t) { vv[t][0] = zero4; vv[t][1] = zero4; }

  const char* wqb = (const char*)wqkvt;
#pragma unroll
  for (int ks = 0; ks < 4; ++ks) {
    u16x8 xb[4];
#pragma unroll
    for (int t = 0; t < 4; ++t) {
      int row = t * 16 + q15;
      int byte = row * 256 + ((ks * 64 + g * 16) ^ ((row & 7) << 4));
      xb[t] = *(const u16x8*)((const char*)xs + byte);
    }
    const int kb = ks * 64 + g * 16;
    u16x8 wq[2], wk[2], wv[2];
#pragma unroll
    for (int m = 0; m < 2; ++m) {
      int col = h * 32 + m * 16 + q15;
      wq[m] = *(const u16x8*)(wqb + (size_t)col * 256 + kb);
      wk[m] = *(const u16x8*)(wqb + (size_t)(col + 128) * 256 + kb);
      wv[m] = *(const u16x8*)(wqb + (size_t)(col + 256) * 256 + kb);
    }
#pragma unroll
    for (int m = 0; m < 2; ++m)
#pragma unroll
      for (int t = 0; t < 4; ++t) {
        qt[m][t] = mfma32(wq[m], xb[t], qt[m][t]);  // Q^T tile [c 16m][tok 16t]
        kt[m][t] = mfma32(wk[m], xb[t], kt[m][t]);
      }
#pragma unroll
    for (int t = 0; t < 4; ++t)
#pragma unroll
      for (int n = 0; n < 2; ++n)
        vv[t][n] = mfma32(xb[t], wv[n], vv[t][n]);  // V tile [tok 16t][d 16n]
  }
  __syncthreads();  // all xs reads done; xs free for attn-out staging

  // ---- in-lane repacks ----
  u16x4 qp[2][4], kp[2][4], vp[4][2];
#pragma unroll
  for (int m = 0; m < 2; ++m)
#pragma unroll
    for (int t = 0; t < 4; ++t) { qp[m][t] = pack4(qt[m][t]); kp[m][t] = pack4(kt[m][t]); }
#pragma unroll
  for (int t = 0; t < 4; ++t) { vp[t][0] = pack4(vv[t][0]); vp[t][1] = pack4(vv[t][1]); }

  // ---- S^T = K·(Q*scale)^T + bias^T  (bias preloaded in frag layout) ----
  f32x4 st[4][4];
  const f32x4* bst = (const f32x4*)biasst;
#pragma unroll
  for (int mk = 0; mk < 4; ++mk)
#pragma unroll
    for (int nq = 0; nq < 4; ++nq)
      st[mk][nq] = bst[((h * 4 + mk) * 4 + nq) * 64 + lane];
#pragma unroll
  for (int ks = 0; ks < 2; ++ks)
#pragma unroll
    for (int mk = 0; mk < 4; ++mk)
#pragma unroll
      for (int nq = 0; nq < 4; ++nq)
        st[mk][nq] = mfma16(kp[ks][mk], qp[ks][nq], st[mk][nq]);

  // ---- softmax over keys (S^T rows); each lane holds 16 vals/row, + g-group shuffles ----
  float rcp[4];
#pragma unroll
  for (int nq = 0; nq < 4; ++nq) {
    float mx = st[0][nq][0];
#pragma unroll
    for (int mk = 0; mk < 4; ++mk)
#pragma unroll
      for (int i = 0; i < 4; ++i) mx = fmaxf(mx, st[mk][nq][i]);
    mx = fmaxf(mx, __shfl_xor(mx, 16));
    mx = fmaxf(mx, __shfl_xor(mx, 32));
    float s = 0.f;
#pragma unroll
    for (int mk = 0; mk < 4; ++mk)
#pragma unroll
      for (int i = 0; i < 4; ++i) {
        float e = __expf(st[mk][nq][i] - mx);
        st[mk][nq][i] = e;
        s += e;
      }
    s += __shfl_xor(s, 16);
    s += __shfl_xor(s, 32);
    rcp[nq] = 1.0f / s;
  }

  u16x4 pp[4][4];
#pragma unroll
  for (int mk = 0; mk < 4; ++mk)
#pragma unroll
    for (int nq = 0; nq < 4; ++nq) pp[mk][nq] = pack4(st[mk][nq]);

  // ---- out^T = V^T · P^T ----
  f32x4 ot[2][4];
#pragma unroll
  for (int md = 0; md < 2; ++md)
#pragma unroll
    for (int nq = 0; nq < 4; ++nq) ot[md][nq] = zero4;
#pragma unroll
  for (int ks = 0; ks < 4; ++ks)
#pragma unroll
    for (int md = 0; md < 2; ++md)
#pragma unroll
      for (int nq = 0; nq < 4; ++nq)
        ot[md][nq] = mfma16(vp[ks][md], pp[ks][nq], ot[md][nq]);

  // ---- epilogue: divide by softmax sum, stage attn-out bf16 into xs ----
#pragma unroll
  for (int md = 0; md < 2; ++md)
#pragma unroll
    for (int nq = 0; nq < 4; ++nq) {
      int qtok = nq * 16 + q15;
      int cb2 = (h * 32 + md * 16 + g * 4) * 2;
      uint2 w;
      w.x = pk2(ot[md][nq][0] * rcp[nq], ot[md][nq][1] * rcp[nq]);
      w.y = pk2(ot[md][nq][2] * rcp[nq], ot[md][nq][3] * rcp[nq]);
      int byte = qtok * 256 + (cb2 ^ ((qtok & 7) << 4));
      *(uint2*)((char*)xs + byte) = w;
    }
  __syncthreads();  // attn-out complete for all heads

  // ---- proj GEMM: out = attn_out · Wproj + b ----
  f32x4 pr[4][2];
#pragma unroll
  for (int t = 0; t < 4; ++t) { pr[t][0] = zero4; pr[t][1] = zero4; }
  const char* wpb = (const char*)wprojt;
#pragma unroll
  for (int ks = 0; ks < 4; ++ks) {
    u16x8 ax[4];
#pragma unroll
    for (int t = 0; t < 4; ++t) {
      int row = t * 16 + q15;
      int byte = row * 256 + ((ks * 64 + g * 16) ^ ((row & 7) << 4));
      ax[t] = *(const u16x8*)((const char*)xs + byte);
    }
    u16x8 wp[2];
#pragma unroll
    for (int n = 0; n < 2; ++n)
      wp[n] = *(const u16x8*)(wpb + (size_t)(h * 32 + n * 16 + q15) * 256 + ks * 64 + g * 16);
#pragma unroll
    for (int t = 0; t < 4; ++t)
#pragma unroll
      for (int n = 0; n < 2; ++n)
        pr[t][n] = mfma32(ax[t], wp[n], pr[t][n]);
  }
  float* op = out + wbase;
#pragma unroll
  for (int n = 0; n < 2; ++n) {
    float bv = bproj[h * 32 + n * 16 + q15];
#pragma unroll
    for (int t = 0; t < 4; ++t)
#pragma unroll
      for (int i = 0; i < 4; ++i)
        op[(size_t)(t * 16 + g * 4 + i) * CDIM + (h * 32 + n * 16 + q15)] = pr[t][n][i] + bv;
  }
}

extern "C" void kernel_launch(void* const* d_in, const int* in_sizes, int n_in,
                              void* d_out, int out_size, void* d_ws, size_t ws_size,
                              hipStream_t stream) {
  const float* x     = (const float*)d_in[0];
  const float* wqkv  = (const float*)d_in[1];
  const float* wproj = (const float*)d_in[2];
  const float* bproj = (const float*)d_in[3];
  const float* btab  = (const float*)d_in[4];
  char* ws = (char*)d_ws;
  unsigned short* wqkvt  = (unsigned short*)ws;             // 98304 B
  unsigned short* wprojt = (unsigned short*)(ws + 98304);   // 32768 B
  float* biasst          = (float*)(ws + 131072);           // 65536 B

  prep_kernel<<<320, 256, 0, stream>>>(wqkv, wproj, btab, wqkvt, wprojt, biasst);
  attn_kernel<<<4096, 256, 0, stream>>>(x, wqkvt, wprojt, biasst, bproj, (float*)d_out);
}